// Round 5
// baseline (136.096 us; speedup 1.0000x reference)
//
#include <hip/hip_runtime.h>

// xDeepFM CIN, MI355X (gfx950) — R14: wave re-slice (bp,nh) in cin_h.
// R13 post-mortem: frag-ordered pW -8.2us (total 132.3); cin_h still 55us =
// dominant. Model: MFMA-busy 23.7us == floor, VALU 20us, ~2 lockstep
// waves/SIMD => bursts serialize. VALU is B-operand build: 32 pk_mul per
// 8 MFMA (4:1), duplicated across the two g-waves of a batch-pair.
// R14: wave = (bp, nh) — each wave does BOTH o-halves for its k-half.
// Per j: 4 products (16 pk_mul) each feeding 2 MFMAs (both g) => 2:1.
// W-frags per wave double (4/j, both g) — L2-resident, ~62B/cyc L1 path.
// p-chunks, barriers, R13 fragment-ordered pW, cin_out: unchanged.

typedef _Float16 f16;
typedef _Float16 f16x4 __attribute__((ext_vector_type(4)));
typedef _Float16 f16x8 __attribute__((ext_vector_type(8)));
typedef float f32x4 __attribute__((ext_vector_type(4)));
typedef float f32x16 __attribute__((ext_vector_type(16)));

#define HSTR 72      // h LDS row stride (f16): 144B = 9*16B, b128-aligned
#define GSTR 163840  // pW per-32-batch-group stride (f16): 320 frags * 512
#define P0G  0       // p0 frags [0,64)   within group
#define P1G  32768   // p1 frags [0,128)  within group
#define P2G  98304   // p2 frags [0,128)  within group

__device__ __forceinline__ f32x16 zero16() {
    f32x16 v;
#pragma unroll
    for (int i = 0; i < 16; ++i) v[i] = 0.0f;
    return v;
}

// ---------------- prep: W (fp32 row-major) -> f16 fragment-ordered ----------
// Fragment (mc, kk) = 512 f16; element lane*8+i =
//   W[rbase + mc*32 + (lane&31)][kk*16 + (lane>>5)*8 + i]
// Regions (f16 offsets): H0@0 (W0 r0..63, KK=64) | O0@65536 (W0 r64..127) |
// H1@131072 (W1 r0..63, KK=128) | O1@262144 (W1 r64..127) | O2@393216 (W2 all).
__global__ void __launch_bounds__(256)
prep_frag(const float* __restrict__ W0, const float* __restrict__ W1,
          const float* __restrict__ W2, f16* __restrict__ dst)
{
    int g = (blockIdx.x * 256 + threadIdx.x) * 8;    // grid = 320
    const float* src; int base, KK, rbase;
    if (g < 65536)       { src = W0; base = 0;      KK = 64;  rbase = 0;  }
    else if (g < 131072) { src = W0; base = 65536;  KK = 64;  rbase = 64; }
    else if (g < 262144) { src = W1; base = 131072; KK = 128; rbase = 0;  }
    else if (g < 393216) { src = W1; base = 262144; KK = 128; rbase = 64; }
    else                 { src = W2; base = 393216; KK = 128; rbase = 0;  }
    int local = g - base;
    int frag  = local >> 9;
    int lane  = (local >> 3) & 63;
    int kk    = frag % KK;
    int mc    = frag / KK;
    int row   = rbase + mc * 32 + (lane & 31);
    int col   = kk * 16 + (lane >> 5) * 8;
    int IC    = KK * 16;
    const float* s = src + (size_t)row * IC + col;
    f16x8 o;
#pragma unroll
    for (int i = 0; i < 8; ++i) o[i] = (f16)s[i];
    *(f16x8*)(dst + g) = o;
}

// ---- p-chunk: P rows [jb, jb+32) of one batch (M=32 j, N=32 z, K=64) ------
// Writes fragment-ordered: pdst = groupbase + regionoff + (b&31)*8.
__device__ __forceinline__ void p_chunk(const f16* __restrict__ hrows,
                                        const f16x8 (&pB)[4],
                                        f16* __restrict__ pdst, int jb,
                                        int t, int q)
{
    f32x16 acc = zero16();
#pragma unroll
    for (int s = 0; s < 4; ++s) {
        f16x8 a = *(const f16x8*)(hrows + t * HSTR + s * 16 + q * 8);
        acc = __builtin_amdgcn_mfma_f32_32x32x16_f16(a, pB[s], acc, 0, 0, 0);
    }
#pragma unroll
    for (int r = 0; r < 16; ++r) {
        int j = jb + (r & 3) + 8 * (r >> 2) + 4 * q;
        int f = j * 2 + (t >> 4);
        pdst[f * 512 + ((t >> 3) & 1) * 256 + (t & 7)] = (f16)acc[r];
    }
}

// ---- h-GEMM (R14): wave = (bp, nh): BOTH o-halves, own k-half --------------
// Per j: 4 W-frag loads (g x kq), 2 h-scalar reads, 4 products (16 pk_mul)
// each feeding 2 MFMAs (both g) -> 8 MFMAs. Ping-pong depth-2.
template <int HJ, int KKG>   // KKG = fragments per g-half region (= 2*HJ)
__device__ __forceinline__ void h_gemm_bn(const f16* __restrict__ Hf,
                                          const f16* __restrict__ h0,
                                          const f16* __restrict__ h1,
                                          int lane8, int t, int nh,
                                          const f16x8 (&ip)[2][2],   // [b][kq]
                                          f32x16 (&acc)[2][2])       // [b][g]
{
    acc[0][0] = zero16(); acc[0][1] = zero16();
    acc[1][0] = zero16(); acc[1][1] = zero16();
    const f16* Wp0 = Hf + lane8;                // g = 0
    const f16* Wp1 = Hf + (size_t)KKG * 512 + lane8;    // g = 1
    f16x8 wf[2][2][2];   // [phase][g][kq]
    f16   sc[2][2];      // [phase][b]
#pragma unroll
    for (int ph = 0; ph < 2; ++ph) {
        wf[ph][0][0] = *(const f16x8*)(Wp0 + (ph * 2 + 0) * 512);
        wf[ph][0][1] = *(const f16x8*)(Wp0 + (ph * 2 + 1) * 512);
        wf[ph][1][0] = *(const f16x8*)(Wp1 + (ph * 2 + 0) * 512);
        wf[ph][1][1] = *(const f16x8*)(Wp1 + (ph * 2 + 1) * 512);
        sc[ph][0] = h0[ph * HSTR + nh * 32 + t];
        sc[ph][1] = h1[ph * HSTR + nh * 32 + t];
    }
    for (int jj = 0; jj < HJ; jj += 2) {
#pragma unroll
        for (int ph = 0; ph < 2; ++ph) {
            f16x8 w00 = wf[ph][0][0], w01 = wf[ph][0][1];
            f16x8 w10 = wf[ph][1][0], w11 = wf[ph][1][1];
            f16 s0 = sc[ph][0], s1 = sc[ph][1];
            int jn = jj + ph + 2;
            if (jn > HJ - 1) jn = HJ - 1;              // clamped refill
            wf[ph][0][0] = *(const f16x8*)(Wp0 + (jn * 2 + 0) * 512);
            wf[ph][0][1] = *(const f16x8*)(Wp0 + (jn * 2 + 1) * 512);
            wf[ph][1][0] = *(const f16x8*)(Wp1 + (jn * 2 + 0) * 512);
            wf[ph][1][1] = *(const f16x8*)(Wp1 + (jn * 2 + 1) * 512);
            sc[ph][0] = h0[jn * HSTR + nh * 32 + t];
            sc[ph][1] = h1[jn * HSTR + nh * 32 + t];
            f16x8 p00 = ip[0][0] * s0;   // batch0, kq=0 — feeds both g
            f16x8 p01 = ip[0][1] * s0;   // batch0, kq=1
            f16x8 p10 = ip[1][0] * s1;   // batch1, kq=0
            f16x8 p11 = ip[1][1] * s1;   // batch1, kq=1
            acc[0][0] = __builtin_amdgcn_mfma_f32_32x32x16_f16(w00, p00, acc[0][0], 0, 0, 0);
            acc[0][0] = __builtin_amdgcn_mfma_f32_32x32x16_f16(w01, p01, acc[0][0], 0, 0, 0);
            acc[0][1] = __builtin_amdgcn_mfma_f32_32x32x16_f16(w10, p00, acc[0][1], 0, 0, 0);
            acc[0][1] = __builtin_amdgcn_mfma_f32_32x32x16_f16(w11, p01, acc[0][1], 0, 0, 0);
            acc[1][0] = __builtin_amdgcn_mfma_f32_32x32x16_f16(w00, p10, acc[1][0], 0, 0, 0);
            acc[1][0] = __builtin_amdgcn_mfma_f32_32x32x16_f16(w01, p11, acc[1][0], 0, 0, 0);
            acc[1][1] = __builtin_amdgcn_mfma_f32_32x32x16_f16(w10, p10, acc[1][1], 0, 0, 0);
            acc[1][1] = __builtin_amdgcn_mfma_f32_32x32x16_f16(w11, p11, acc[1][1], 0, 0, 0);
        }
    }
}

__device__ __forceinline__ void load_bias(const float* __restrict__ bl,
                                          float (&bve)[16], int g, int q)
{
#pragma unroll
    for (int r = 0; r < 16; ++r)
        bve[r] = bl[g * 32 + (r & 3) + 8 * (r >> 2) + 4 * q];
}

// Write h_{l+1}: both g-halves (rows 0..63), cols nh*32+t, both batches.
__device__ __forceinline__ void epi_bn(const f32x16 (&acc)[2][2],
                                       f16* __restrict__ h0d, f16* __restrict__ h1d,
                                       const float (&bv0)[16], const float (&bv1)[16],
                                       int nh, int t, int q)
{
#pragma unroll
    for (int r = 0; r < 16; ++r) {
        int ro = (r & 3) + 8 * (r >> 2) + 4 * q;
        int c  = nh * 32 + t;
        h0d[ro * HSTR + c]        = (f16)(acc[0][0][r] + bv0[r]);
        h0d[(32 + ro) * HSTR + c] = (f16)(acc[0][1][r] + bv1[r]);
        h1d[ro * HSTR + c]        = (f16)(acc[1][0][r] + bv0[r]);
        h1d[(32 + ro) * HSTR + c] = (f16)(acc[1][1][r] + bv1[r]);
    }
}

// =================== Kernel 1: h-chain + p-vectors =========================
__global__ void __launch_bounds__(256, 2)
cin_h(const float* __restrict__ inp, const f16* __restrict__ Wf,
      f16* __restrict__ pW,
      const float* __restrict__ b0v, const float* __restrict__ b1v)
{
    __shared__ __attribute__((aligned(16))) f16 hL[4 * 64 * HSTR];  // 36864 B

    const int tid   = threadIdx.x;
    const int w     = tid >> 6;
    const int lane  = tid & 63;
    const int t     = lane & 31;
    const int q     = lane >> 5;
    const int lane8 = lane * 8;
    const int nh    = w & 1;          // k-half
    const int bp    = w >> 1;         // batch-pair (local batches bp*2, bp*2+1)
    const int b0i   = blockIdx.x * 4;

    // Stage: 4 batches x 32 z-rows of inp (f32 coalesced) -> hL rows 0..31.
#pragma unroll
    for (int it = 0; it < 8; ++it) {
        int idx = it * 1024 + tid * 4;
        int b = idx >> 11, rem = idx & 2047;
        int z = rem >> 6, k = rem & 63;
        f32x4 v = *(const f32x4*)(inp + (size_t)(b0i + b) * 2048 + rem);
        f16x4 h4;
        h4[0] = (f16)v[0]; h4[1] = (f16)v[1]; h4[2] = (f16)v[2]; h4[3] = (f16)v[3];
        *(f16x4*)(hL + b * 64 * HSTR + z * HSTR + k) = h4;
    }
    __syncthreads();                                   // B0: h0 (=inp) ready

    // ip[b][kq][i] = inp[bp*2+b][z=kq*16+q*8+i][nh*32+t]  (own k-half only)
    f16x8 ip[2][2];
#pragma unroll
    for (int b = 0; b < 2; ++b) {
        const f16* src = hL + (bp * 2 + b) * 64 * HSTR;
#pragma unroll
        for (int kq = 0; kq < 2; ++kq) {
            f16x8 v;
#pragma unroll
            for (int i = 0; i < 8; ++i)
                v[i] = src[(kq * 16 + q * 8 + i) * HSTR + nh * 32 + t];
            ip[b][kq] = v;
        }
    }
    // pB[s][i] = inp[w][z=t][k=s*16+q*8+i] — p-GEMM B-frags (wave w <-> batch w)
    f16x8 pB[4];
#pragma unroll
    for (int s = 0; s < 4; ++s)
        pB[s] = *(const f16x8*)(hL + w * 64 * HSTR + t * HSTR + s * 16 + q * 8);

    const int bglob = b0i + w;        // wave w <-> batch w (p-work only)
    f16* pG = pW + (size_t)(bglob >> 5) * GSTR + (bglob & 31) * 8;
    const f16* H0 = Wf;
    const f16* H1 = Wf + 131072;
    f16* hA = hL + (bp * 2) * 64 * HSTR;
    f16* hB = hL + (bp * 2 + 1) * 64 * HSTR;
    f32x16 acc[2][2];
    float bv0[16], bv1[16];

    // ---- Layer 0 (HJ=32) ----
    p_chunk(hL + w * 64 * HSTR, pB, pG + P0G, 0, t, q);     // p0 j 0..31
    h_gemm_bn<32, 64>(H0, hA, hB, lane8, t, nh, ip, acc);
    load_bias(b0v, bv0, 0, q);
    load_bias(b0v, bv1, 1, q);
    __syncthreads();                                   // B1: all h0 reads done
    epi_bn(acc, hA, hB, bv0, bv1, nh, t, q);           // h1 (rows 0..63)
    __syncthreads();                                   // B2: h1 ready

    // ---- Layer 1 (HJ=64) ----
    p_chunk(hL + w * 64 * HSTR,             pB, pG + P1G, 0,  t, q);
    p_chunk(hL + w * 64 * HSTR + 32 * HSTR, pB, pG + P1G, 32, t, q);
    h_gemm_bn<64, 128>(H1, hA, hB, lane8, t, nh, ip, acc);
    load_bias(b1v, bv0, 0, q);
    load_bias(b1v, bv1, 1, q);
    __syncthreads();                                   // B3: all h1 reads done
    epi_bn(acc, hA, hB, bv0, bv1, nh, t, q);           // h1 -> h2 in place
    __syncthreads();                                   // B4: h2 ready

    p_chunk(hL + w * 64 * HSTR,             pB, pG + P2G, 0,  t, q);
    p_chunk(hL + w * 64 * HSTR + 32 * HSTR, pB, pG + P2G, 32, t, q);
}

// =================== Kernel 2: out GEMMs (N = batch), R13 ==================
// Block = 512 thr (8 waves): mi = M-half, ki = K-quarter. B-frags 1KB
// wave-coalesced (fragment-ordered pW); mi-pair reads identical addresses
// (L1 share). Depth-8 prefetch ring. 4-way K partials reduced via 32KB LDS.
template <int KK>   // KK = total K-fragments (region0: 64, others: 128)
__device__ __forceinline__ void o_tile(const f16* __restrict__ Of,
                                       const f16* __restrict__ pBase,
                                       const float* __restrict__ biasp,
                                       float* __restrict__ out,
                                       float* __restrict__ rP,
                                       int bg, int colbase, int tid)
{
    const int w = tid >> 6, lane = tid & 63, t = lane & 31, q = lane >> 5;
    const int lane8 = lane * 8;
    const int mi = w & 1, ki = w >> 1;           // mi pairs adjacent -> B share
    const int SQ = KK / 4;                       // K-frags per wave (16 or 32)
    const f16* Ap = Of + (size_t)(mi * KK + ki * SQ) * 512 + lane8;
    const f16* Bp = pBase + (size_t)(ki * SQ) * 512 + lane8;

    f32x16 acc = zero16();
    f16x8 af[8], bf[8];
#pragma unroll
    for (int i = 0; i < 8; ++i) {
        af[i] = *(const f16x8*)(Ap + i * 512);
        bf[i] = *(const f16x8*)(Bp + i * 512);
    }
#pragma unroll 8
    for (int s = 0; s < SQ; ++s) {
        int idx = s & 7;
        f16x8 a = af[idx], b = bf[idx];
        int sn = s + 8 < SQ ? s + 8 : SQ - 1;    // clamped refill
        af[idx] = *(const f16x8*)(Ap + sn * 512);
        bf[idx] = *(const f16x8*)(Bp + sn * 512);
        acc = __builtin_amdgcn_mfma_f32_32x32x16_f16(a, b, acc, 0, 0, 0);
    }
#pragma unroll
    for (int r = 0; r < 16; ++r) {
        int m = mi * 32 + (r & 3) + 8 * (r >> 2) + 4 * q;
        rP[(ki * 32 + t) * 64 + m] = acc[r];
    }
    __syncthreads();
    // Combine: 512 thr x f32x4 = 2048 f32 (32 batches x 64 cols).
    {
        int n = tid >> 4;            // batch row 0..31
        int o = (tid & 15) * 4;      // col 0..60
        f32x4 v = *(const f32x4*)(rP + n * 64 + o);
#pragma unroll
        for (int k2 = 1; k2 < 4; ++k2) {
            f32x4 u = *(const f32x4*)(rP + (k2 * 32 + n) * 64 + o);
            v[0] += u[0]; v[1] += u[1]; v[2] += u[2]; v[3] += u[3];
        }
        f32x4 bb = *(const f32x4*)(biasp + o);
        v[0] += 64.0f * bb[0]; v[1] += 64.0f * bb[1];
        v[2] += 64.0f * bb[2]; v[3] += 64.0f * bb[3];
        *(f32x4*)(out + (size_t)(bg * 32 + n) * 256 + colbase + o) = v;
    }
}

__global__ void __launch_bounds__(512, 2)
cin_out(const f16* __restrict__ Wf, const f16* __restrict__ pW,
        const float* __restrict__ b0v, const float* __restrict__ b1v,
        const float* __restrict__ b2v, float* __restrict__ out)
{
    __shared__ __attribute__((aligned(16))) float rP[4 * 32 * 64];  // 32 KB
    const int tid = threadIdx.x;
    const int r  = blockIdx.x & 3;      // region
    const int bg = blockIdx.x >> 2;     // 32-batch group (64 of them)
    const f16* pGrp = pW + (size_t)bg * GSTR;
    if (r == 0)
        o_tile<64> (Wf + 65536,  pGrp + P0G, b0v + 64, out, rP, bg, 0,   tid);
    else if (r == 1)
        o_tile<128>(Wf + 262144, pGrp + P1G, b1v + 64, out, rP, bg, 64,  tid);
    else if (r == 2)
        o_tile<128>(Wf + 393216, pGrp + P2G, b2v,      out, rP, bg, 128, tid);
    else
        o_tile<128>(Wf + 524288, pGrp + P2G, b2v + 64, out, rP, bg, 192, tid);
}

extern "C" void kernel_launch(void* const* d_in, const int* in_sizes, int n_in,
                              void* d_out, int out_size, void* d_ws, size_t ws_size,
                              hipStream_t stream)
{
    const float* inp = (const float*)d_in[0];
    const float* W0  = (const float*)d_in[1];
    const float* b0  = (const float*)d_in[2];
    const float* W1  = (const float*)d_in[3];
    const float* b1  = (const float*)d_in[4];
    const float* W2  = (const float*)d_in[5];
    const float* b2  = (const float*)d_in[6];
    float* out = (float*)d_out;

    f16* Wf = (f16*)d_ws;             // 655360 f16 = 1.25 MB fragment-ordered
    f16* pW = Wf + 655360;            // 64 groups * 163840 f16 = 20 MB

    prep_frag<<<320, 256, 0, stream>>>(W0, W1, W2, Wf);
    cin_h<<<512, 256, 0, stream>>>(inp, Wf, pW, b0, b1);
    cin_out<<<256, 512, 0, stream>>>(Wf, pW, b0, b1, b2, out);
}